// Round 5
// baseline (30.855 us; speedup 1.0000x reference)
//
#include <hip/hip_runtime.h>
#include <float.h>

#define BATCH 64
#define NROWS 8192
#define NCH   64
#define TOPK  9
#define TPB   1024
#define CGRP  4              // channel groups (blocks per batch)
#define CHB   (NCH / CGRP)   // 16 channels per block
#define SLOTS 256            // thread-local lists per channel (TPB/4)

// Insert v into descending-sorted m[0..8], keep top-9.
// r[0] = max(m[0], v); r[k] = median(m[k-1], m[k], v)  -- depth-1, 9 ops.
__device__ __forceinline__ void insert9(float (&m)[TOPK], float v) {
    const float r0 = fmaxf(m[0], v);
#pragma unroll
    for (int k = TOPK - 1; k >= 1; --k)
        m[k] = __builtin_amdgcn_fmed3f(m[k - 1], m[k], v);
    m[0] = r0;
}

// One block = (batch b, channel-group cg): top-9 per channel over all 8192
// rows, entirely in-block -> no second kernel, no cross-block sync.
// 144 KB LDS forces 1 block/CU -> 256 blocks fill all 256 CUs.
__global__ __launch_bounds__(TPB) void topk_onepass(const float* __restrict__ x,
                                                    float* __restrict__ out) {
    // bx -> (b,cg) swizzle: sibling blocks (cg pairs {0,1},{2,3} share the
    // same 128B row-lines) get equal bx%8 -> same XCD under round-robin.
    const int bx = blockIdx.x;
    const int x3     = bx & 7;
    const int y      = bx >> 3;
    const int member = y >> 4;        // 0..1
    const int pg     = y & 15;        // 0..15
    const int pid    = pg * 8 + x3;   // 0..127
    const int b      = pid >> 1;
    const int cg     = ((pid & 1) << 1) | member;

    const int t     = threadIdx.x;
    const int chunk = t & 3;          // which float4 (4 channels) of block's 16
    const int slot  = t >> 2;         // 0..255: row subset

    float m[4][TOPK];
#pragma unroll
    for (int ci = 0; ci < 4; ++ci)
#pragma unroll
        for (int k = 0; k < TOPK; ++k) m[ci][k] = -FLT_MAX;

    // Stream: thread reads float4 (4 ch) of rows slot, slot+256, ... (32 rows).
    // Wave footprint per iter: 16 rows x 64B aligned segments.
    const float4* xb = (const float4*)(x + (size_t)b * NROWS * NCH + cg * CHB);
#pragma unroll 8
    for (int it = 0; it < NROWS / SLOTS; ++it) {
        const float4 v = xb[(slot + it * SLOTS) * (NCH / 4) + chunk];
        insert9(m[0], v.x);
        insert9(m[1], v.y);
        insert9(m[2], v.z);
        insert9(m[3], v.w);
    }

    __shared__ float lists[CHB][SLOTS][TOPK];   // 144 KB
#pragma unroll
    for (int ci = 0; ci < 4; ++ci)
#pragma unroll
        for (int k = 0; k < TOPK; ++k)
            lists[chunk * 4 + ci][slot][k] = m[ci][k];
    __syncthreads();

    // Level 1: 1024 threads; (ch = t>>6, j0 = t&63) merges slots
    // {j0, j0+64, j0+128, j0+192} -> slot j0. Lane stride 9 words: conflict-free.
    {
        const int ch = t >> 6, j0 = t & 63;
        float mm[TOPK];
#pragma unroll
        for (int k = 0; k < TOPK; ++k) mm[k] = lists[ch][j0][k];
#pragma unroll
        for (int i = 1; i < 4; ++i)
#pragma unroll
            for (int k = 0; k < TOPK; ++k)
                insert9(mm, lists[ch][j0 + 64 * i][k]);
#pragma unroll
        for (int k = 0; k < TOPK; ++k) lists[ch][j0][k] = mm[k];
    }
    __syncthreads();

    // Level 2: 256 threads; (ch = t>>4, j1 = t&15): {j1,+16,+32,+48} -> j1.
    if (t < 256) {
        const int ch = t >> 4, j1 = t & 15;
        float mm[TOPK];
#pragma unroll
        for (int k = 0; k < TOPK; ++k) mm[k] = lists[ch][j1][k];
#pragma unroll
        for (int i = 1; i < 4; ++i)
#pragma unroll
            for (int k = 0; k < TOPK; ++k)
                insert9(mm, lists[ch][j1 + 16 * i][k]);
#pragma unroll
        for (int k = 0; k < TOPK; ++k) lists[ch][j1][k] = mm[k];
    }
    __syncthreads();

    // Level 3: 64 threads; (ch = t>>2, j2 = t&3): {j2,+4,+8,+12} -> j2.
    if (t < 64) {
        const int ch = t >> 2, j2 = t & 3;
        float mm[TOPK];
#pragma unroll
        for (int k = 0; k < TOPK; ++k) mm[k] = lists[ch][j2][k];
#pragma unroll
        for (int i = 1; i < 4; ++i)
#pragma unroll
            for (int k = 0; k < TOPK; ++k)
                insert9(mm, lists[ch][j2 + 4 * i][k]);
#pragma unroll
        for (int k = 0; k < TOPK; ++k) lists[ch][j2][k] = mm[k];
    }
    __syncthreads();

    // Level 4: 16 threads; merge slots 0..3 of channel t, mean, store.
    if (t < CHB) {
        float mm[TOPK];
#pragma unroll
        for (int k = 0; k < TOPK; ++k) mm[k] = lists[t][0][k];
#pragma unroll
        for (int i = 1; i < 4; ++i)
#pragma unroll
            for (int k = 0; k < TOPK; ++k)
                insert9(mm, lists[t][i][k]);
        float sum = 0.f;
#pragma unroll
        for (int k = 0; k < TOPK; ++k) sum += mm[k];
        out[b * NCH + cg * CHB + t] = sum * (1.0f / 9.0f);
    }
}

extern "C" void kernel_launch(void* const* d_in, const int* in_sizes, int n_in,
                              void* d_out, int out_size, void* d_ws, size_t ws_size,
                              hipStream_t stream) {
    const float* x = (const float*)d_in[0];
    float* out = (float*)d_out;
    topk_onepass<<<BATCH * CGRP, TPB, 0, stream>>>(x, out);
}